// Round 3
// baseline (45.092 us; speedup 1.0000x reference)
//
#include <hip/hip_runtime.h>

// FK over the SMPL joint tree, LDS-transposed for coalescing, split into two
// joint-halves to cut LDS per frame (264 B/half) and raise occupancy.
//
// Block = 64 threads = 1 wave = 64 frames. Per half: stage 66 floats/frame
// (coalesced float2), compute 11 joints per thread from its LDS row, write
// the 6 output floats per joint in place, store coalesced. The only
// cross-half parents are joints 8 and 9 -> Rg[8], Rg[9] stay in registers
// across the passes. Linear LDS rows (stride 66 floats): lane bank stride
// 66 % 32 = 2 -> 2-way conflict, which is free on CDNA4.

#define FPB 64       // frames per block == threads per block (1 wave)
#define HALF_F2 33   // float2s per half-frame (66 floats = 11 joints)

__device__ __forceinline__ void local_rot(const float* __restrict__ s, float* __restrict__ L) {
    float a1x = s[0], a1y = s[1], a1z = s[2];
    float a2x = s[3], a2y = s[4], a2z = s[5];
    float n1 = sqrtf(a1x * a1x + a1y * a1y + a1z * a1z);
    float i1 = 1.0f / fmaxf(n1, 1e-12f);
    float b1x = a1x * i1, b1y = a1y * i1, b1z = a1z * i1;
    float dt = b1x * a2x + b1y * a2y + b1z * a2z;
    float cx = a2x - dt * b1x, cy = a2y - dt * b1y, cz = a2z - dt * b1z;
    float n2 = sqrtf(cx * cx + cy * cy + cz * cz);
    float i2 = 1.0f / fmaxf(n2, 1e-12f);
    float b2x = cx * i2, b2y = cy * i2, b2z = cz * i2;
    L[0] = b1x; L[1] = b1y; L[2] = b1z;
    L[3] = b2x; L[4] = b2y; L[5] = b2z;
    L[6] = b1y * b2z - b1z * b2y;
    L[7] = b1z * b2x - b1x * b2z;
    L[8] = b1x * b2y - b1y * b2x;
}

__device__ __forceinline__ void matmul3(float* __restrict__ G,
                                        const float* __restrict__ P,
                                        const float* __restrict__ L) {
#pragma unroll
    for (int r = 0; r < 3; ++r)
#pragma unroll
        for (int c = 0; c < 3; ++c)
            G[3 * r + c] = P[3 * r + 0] * L[0 + c] +
                           P[3 * r + 1] * L[3 + c] +
                           P[3 * r + 2] * L[6 + c];
}

__global__ __launch_bounds__(FPB) void fk6d_kernel(const float* __restrict__ in,
                                                   float* __restrict__ out,
                                                   int N)
{
    constexpr int PAR[22] = {0, 0, 0, 0, 1, 2, 3, 4, 5, 6, 7, 8, 9, 9, 9,
                             12, 13, 14, 16, 17, 18, 19};
    __shared__ float lds[FPB * 66];  // 16896 B
    float2* __restrict__ lbuf2 = reinterpret_cast<float2*>(lds);

    const int tid = threadIdx.x;
    const int F0 = blockIdx.x * FPB;
    const int frames_here = min(FPB, N - F0);
    const int total2 = frames_here * HALF_F2;
    const float2* __restrict__ gin2 = reinterpret_cast<const float2*>(in);
    float2* __restrict__ gout2 = reinterpret_cast<float2*>(out);
    const size_t gbase2 = (size_t)F0 * 66;  // 66 float2 per full frame

    float Rg[22][9];  // fully statically indexed after unroll -> registers

    // ================= pass A: joints 0..10 =================
    for (int v = tid; v < total2; v += FPB) {
        int f = v / HALF_F2;  // magic-mul
        lbuf2[v] = gin2[gbase2 + (size_t)f * HALF_F2 + v];  // half A: +33f
    }
    __syncthreads();

    if (tid < frames_here) {
        float* __restrict__ row = lds + tid * 66;
#pragma unroll
        for (int j = 0; j < 11; ++j) {
            float L[9];
            local_rot(row + 6 * j, L);
            if (j == 0) {
#pragma unroll
                for (int k = 0; k < 9; ++k) Rg[0][k] = L[k];
            } else {
                matmul3(Rg[j], Rg[PAR[j]], L);
            }
#pragma unroll
            for (int k = 0; k < 6; ++k) row[6 * j + k] = Rg[j][k];
        }
    }
    __syncthreads();

    for (int v = tid; v < total2; v += FPB) {
        int f = v / HALF_F2;
        gout2[gbase2 + (size_t)f * HALF_F2 + v] = lbuf2[v];
    }
    __syncthreads();  // stores must read LDS before pass B overwrites it

    // ================= pass B: joints 11..21 =================
    for (int v = tid; v < total2; v += FPB) {
        int f = v / HALF_F2;
        lbuf2[v] = gin2[gbase2 + (size_t)(f + 1) * HALF_F2 + v];  // half B: +33(f+1)
    }
    __syncthreads();

    if (tid < frames_here) {
        float* __restrict__ row = lds + tid * 66;
#pragma unroll
        for (int j = 11; j < 22; ++j) {
            float L[9];
            local_rot(row + 6 * (j - 11), L);
            matmul3(Rg[j], Rg[PAR[j]], L);  // PAR[j] in {8,9,12..19}; 8,9 carried in regs
#pragma unroll
            for (int k = 0; k < 6; ++k) row[6 * (j - 11) + k] = Rg[j][k];
        }
    }
    __syncthreads();

    for (int v = tid; v < total2; v += FPB) {
        int f = v / HALF_F2;
        gout2[gbase2 + (size_t)(f + 1) * HALF_F2 + v] = lbuf2[v];
    }
}

extern "C" void kernel_launch(void* const* d_in, const int* in_sizes, int n_in,
                              void* d_out, int out_size, void* d_ws, size_t ws_size,
                              hipStream_t stream) {
    const float* in = (const float*)d_in[0];
    float* out = (float*)d_out;
    int N = in_sizes[0] / 132;  // B*T frames
    int grid = (N + FPB - 1) / FPB;
    fk6d_kernel<<<grid, FPB, 0, stream>>>(in, out, N);
}

// Round 4
// 33.137 us; speedup vs baseline: 1.3608x; 1.3608x over previous
//
#include <hip/hip_runtime.h>

// FK over the SMPL joint tree. Single-wave blocks (64 threads = 64 frames),
// async global->LDS staging via global_load_lds width=16 (no VGPR round-trip,
// one vmcnt drain instead of per-chunk latency serialization), full frame per
// thread computed from its LDS row, outputs written in place, coalesced
// dwordx4 store-back. LDS [64][132] f32 row-major (DMA forces linear layout;
// stride 132 -> 8-way bank conflict on compute reads, ~free vs latency win).

#define FPB 64  // frames per block == threads per block == 1 wave

__device__ __forceinline__ void local_rot(const float* s, float* L) {
    float a1x = s[0], a1y = s[1], a1z = s[2];
    float a2x = s[3], a2y = s[4], a2z = s[5];
    float n1 = sqrtf(a1x * a1x + a1y * a1y + a1z * a1z);
    float i1 = 1.0f / fmaxf(n1, 1e-12f);
    float b1x = a1x * i1, b1y = a1y * i1, b1z = a1z * i1;
    float dt = b1x * a2x + b1y * a2y + b1z * a2z;
    float cx = a2x - dt * b1x, cy = a2y - dt * b1y, cz = a2z - dt * b1z;
    float n2 = sqrtf(cx * cx + cy * cy + cz * cz);
    float i2 = 1.0f / fmaxf(n2, 1e-12f);
    float b2x = cx * i2, b2y = cy * i2, b2z = cz * i2;
    L[0] = b1x; L[1] = b1y; L[2] = b1z;
    L[3] = b2x; L[4] = b2y; L[5] = b2z;
    L[6] = b1y * b2z - b1z * b2y;
    L[7] = b1z * b2x - b1x * b2z;
    L[8] = b1x * b2y - b1y * b2x;
}

// Full FK chain for one frame; src and dst may alias (dst[6j..6j+5] is
// written only after src[6j..6j+5] is consumed; later joints never re-read).
__device__ __forceinline__ void fk_frame(const float* src, float* dst) {
    constexpr int PAR[22] = {0, 0, 0, 0, 1, 2, 3, 4, 5, 6, 7, 8, 9, 9, 9,
                             12, 13, 14, 16, 17, 18, 19};
    float Rg[22][9];  // statically indexed after unroll -> registers
#pragma unroll
    for (int j = 0; j < 22; ++j) {
        float L[9];
        local_rot(src + 6 * j, L);
        float* G = Rg[j];
        if (j == 0) {
#pragma unroll
            for (int k = 0; k < 9; ++k) G[k] = L[k];
        } else {
            const float* P = Rg[PAR[j]];  // compile-time index
#pragma unroll
            for (int r = 0; r < 3; ++r)
#pragma unroll
                for (int c = 0; c < 3; ++c)
                    G[3 * r + c] = P[3 * r + 0] * L[0 + c] +
                                   P[3 * r + 1] * L[3 + c] +
                                   P[3 * r + 2] * L[6 + c];
        }
#pragma unroll
        for (int k = 0; k < 6; ++k) dst[6 * j + k] = G[k];
    }
}

__global__ __launch_bounds__(FPB) void fk6d_kernel(const float* __restrict__ in,
                                                   float* __restrict__ out,
                                                   int N)
{
    __shared__ float lds[FPB * 132];  // 33792 B -> 4 blocks/CU
    const int tid = threadIdx.x;
    const int F0 = blockIdx.x * FPB;

    if (F0 + FPB <= N) {
        const float* gin = in + (size_t)F0 * 132;
        float* gout = out + (size_t)F0 * 132;

        // ---- async stage: 33 x 16B/lane, coalesced, LDS-linear [64][132]
#pragma unroll
        for (int k = 0; k < 33; ++k) {
            const float* src = gin + (size_t)(k * 64 + tid) * 4;
            float* dst = lds + k * 64 * 4;  // wave-uniform base; HW adds lane*16
            __builtin_amdgcn_global_load_lds(
                (const __attribute__((address_space(1))) void*)src,
                (__attribute__((address_space(3))) void*)dst, 16, 0, 0);
        }
        __syncthreads();  // drains vmcnt (DMA) before LDS reads

        // ---- compute: one frame per thread, in place in its LDS row
        fk_frame(lds + tid * 132, lds + tid * 132);
        __syncthreads();

        // ---- coalesced store: ds_read_b128 + global_store_dwordx4
#pragma unroll
        for (int k = 0; k < 33; ++k) {
            float4 v = *reinterpret_cast<const float4*>(lds + (size_t)(k * 64 + tid) * 4);
            *reinterpret_cast<float4*>(gout + (size_t)(k * 64 + tid) * 4) = v;
        }
    } else {
        // tail fallback (never taken for N % 64 == 0): direct global per frame
        int n = F0 + tid;
        if (n < N) {
            fk_frame(in + (size_t)n * 132, out + (size_t)n * 132);
        }
    }
}

extern "C" void kernel_launch(void* const* d_in, const int* in_sizes, int n_in,
                              void* d_out, int out_size, void* d_ws, size_t ws_size,
                              hipStream_t stream) {
    const float* in = (const float*)d_in[0];
    float* out = (float*)d_out;
    int N = in_sizes[0] / 132;  // B*T frames = 100352
    int grid = (N + FPB - 1) / FPB;
    fk6d_kernel<<<grid, FPB, 0, stream>>>(in, out, N);
}